// Round 1
// baseline (611.500 us; speedup 1.0000x reference)
//
#include <hip/hip_runtime.h>
#include <math.h>

// Problem constants
#define BB 128
#define TT 256
#define NN 64
#define OO 32
#define EE 32
#define HH 64
#define SS 129
#define BT 32768      // B*T
#define SP 132        // padded state pitch (multiple of 4)

// ---------------------------------------------------------------------------
// Kernel A: state features. One wave per (b,t) row.
// lane l: o = l&31, half = l>>5; reduce over agents n = half, half+2, ... < k
// ---------------------------------------------------------------------------
__global__ __launch_bounds__(256) void k_states(const float* __restrict__ obs,
                                                const int* __restrict__ mask,
                                                float* __restrict__ states) {
    int w = threadIdx.x >> 6;
    int l = threadIdx.x & 63;
    int bt = blockIdx.x * 4 + w;
    int b = bt >> 8;   // T = 256

    // k = number of active agents for this batch row (count-based mask)
    int kv = mask[(b << 6) + l];
    #pragma unroll
    for (int off = 32; off; off >>= 1) kv += __shfl_xor(kv, off);

    int o = l & 31, nh = l >> 5;
    float sum = 0.f, ssq = 0.f, mn = INFINITY, mx = -INFINITY;
    const float* op = obs + ((size_t)bt << 11);   // bt * N * O
    for (int n = nh; n < kv; n += 2) {
        float v = op[(n << 5) + o];
        sum += v;
        ssq = fmaf(v, v, ssq);
        mn = fminf(mn, v);
        mx = fmaxf(mx, v);
    }
    sum += __shfl_xor(sum, 32);
    ssq += __shfl_xor(ssq, 32);
    mn = fminf(mn, __shfl_xor(mn, 32));
    mx = fmaxf(mx, __shfl_xor(mx, 32));

    float kf = (float)kv;
    float mean = sum / fmaxf(kf, 1.f);
    float var = (ssq - kf * mean * mean) / fmaxf(kf - 1.f, 1.f);
    float sd = (kv > 1) ? sqrtf(fmaxf(var, 0.f)) : 0.f;
    if (kv == 0) { mean = 0.f; sd = 0.f; mn = 0.f; mx = 0.f; }

    float* sp = states + (size_t)bt * SP;
    if (l < 32) {
        sp[o] = mean;
        sp[32 + o] = sd;
        sp[64 + o] = mn;
        sp[96 + o] = mx;
    }
    if (l == 0) {
        sp[128] = kf * 0.015625f;   // ratio = k/64 (0 when k==0, matching ref)
        sp[129] = 0.f; sp[130] = 0.f; sp[131] = 0.f;   // zero pad
    }
}

// ---------------------------------------------------------------------------
// Kernel B1: big K=129 GEMM: states(BT x 129) @ Wcat(129 x 192) + bias + act.
// cols 0..63  -> h1  (relu)    cols 64..127 -> t2 (relu)
// cols 128..159 -> b1v (none)  cols 160..191 -> t3 (relu)
// 128 rows/block, 256 threads: 32 row-groups x 8 col-groups, 4x24 per thread.
// ---------------------------------------------------------------------------
__global__ __launch_bounds__(256) void k_mlp1(const float* __restrict__ states,
        const float* __restrict__ w1_1, const float* __restrict__ b1_1,
        const float* __restrict__ w2_1, const float* __restrict__ b2_1,
        const float* __restrict__ wb1,  const float* __restrict__ bb1,
        const float* __restrict__ wb2_1,const float* __restrict__ bb2_1,
        float* __restrict__ h1, float* __restrict__ t2,
        float* __restrict__ b1v, float* __restrict__ t3) {
    __shared__ float wl[SP * 192];   // 101,376 B, zero-padded k=129..131
    __shared__ float bl[192];
    int t = threadIdx.x;

    for (int idx = t; idx < SP * 192; idx += 256) {
        int k = idx / 192;
        int c = idx - k * 192;
        float v = 0.f;
        if (k < SS) {
            if (c < 64)       v = w1_1[k * 64 + c];
            else if (c < 128) v = w2_1[k * 64 + c - 64];
            else if (c < 160) v = wb1[k * 32 + c - 128];
            else              v = wb2_1[k * 32 + c - 160];
        }
        wl[idx] = v;
    }
    if (t < 192) {
        float v;
        if (t < 64)       v = b1_1[t];
        else if (t < 128) v = b2_1[t - 64];
        else if (t < 160) v = bb1[t - 128];
        else              v = bb2_1[t - 160];
        bl[t] = v;
    }
    __syncthreads();

    int cg = t & 7, rg = t >> 3;
    int c0 = cg * 24;
    int row0 = blockIdx.x * 128 + rg * 4;
    float acc[4][24];
    #pragma unroll
    for (int i = 0; i < 4; i++)
        #pragma unroll
        for (int j = 0; j < 24; j++) acc[i][j] = 0.f;

    const float* s0 = states + (size_t)row0 * SP;
    for (int k0 = 0; k0 < SP; k0 += 4) {
        float4 sv[4];
        #pragma unroll
        for (int i = 0; i < 4; i++) sv[i] = *(const float4*)(s0 + i * SP + k0);
        #pragma unroll
        for (int kk = 0; kk < 4; kk++) {
            float wv[24];
            #pragma unroll
            for (int q = 0; q < 6; q++)
                *(float4*)&wv[q * 4] = *(const float4*)&wl[(k0 + kk) * 192 + c0 + q * 4];
            #pragma unroll
            for (int i = 0; i < 4; i++) {
                float s = ((const float*)&sv[i])[kk];
                #pragma unroll
                for (int j = 0; j < 24; j++) acc[i][j] = fmaf(s, wv[j], acc[i][j]);
            }
        }
    }

    #pragma unroll
    for (int i = 0; i < 4; i++) {
        int row = row0 + i;
        #pragma unroll
        for (int j = 0; j < 24; j++) {
            int c = c0 + j;
            float v = acc[i][j] + bl[c];
            if (c < 128 || c >= 160) v = fmaxf(v, 0.f);   // relu (b1v cols skip)
            if (c < 64)       h1[(size_t)row * 64 + c] = v;
            else if (c < 128) t2[(size_t)row * 64 + c - 64] = v;
            else if (c < 160) b1v[(size_t)row * 32 + c - 128] = v;
            else              t3[(size_t)row * 32 + c - 160] = v;
        }
    }
}

// ---------------------------------------------------------------------------
// Kernel B3: w2 = |t2 @ w2_2 + b2_2| (BTx32), b2v = t3 @ wb2_2 + bb2_2 (BT)
// 64 rows/block, 256 threads: 4 threads/row, 8 e-cols each.
// ---------------------------------------------------------------------------
__global__ __launch_bounds__(256) void k_w2(const float* __restrict__ t2,
        const float* __restrict__ t3, const float* __restrict__ w2_2,
        const float* __restrict__ b2_2, const float* __restrict__ wb2_2,
        const float* __restrict__ bb2_2,
        float* __restrict__ w2, float* __restrict__ b2v) {
    __shared__ float wl[64 * 32];
    __shared__ float wb[32];
    __shared__ float bb[32];
    int t = threadIdx.x;
    for (int idx = t; idx < 2048; idx += 256) wl[idx] = w2_2[idx];
    if (t < 32) wb[t] = wb2_2[t];
    if (t >= 32 && t < 64) bb[t - 32] = b2_2[t - 32];
    __syncthreads();

    int r = t >> 2, eq = t & 3;
    int row = blockIdx.x * 64 + r;
    int e0 = eq * 8;
    float acc[8];
    #pragma unroll
    for (int j = 0; j < 8; j++) acc[j] = 0.f;

    const float* tp = t2 + (size_t)row * 64;
    for (int h4 = 0; h4 < 64; h4 += 4) {
        float4 tv = *(const float4*)(tp + h4);
        #pragma unroll
        for (int hh = 0; hh < 4; hh++) {
            float s = ((const float*)&tv)[hh];
            float4 wv0 = *(const float4*)&wl[(h4 + hh) * 32 + e0];
            float4 wv1 = *(const float4*)&wl[(h4 + hh) * 32 + e0 + 4];
            acc[0] = fmaf(s, wv0.x, acc[0]); acc[1] = fmaf(s, wv0.y, acc[1]);
            acc[2] = fmaf(s, wv0.z, acc[2]); acc[3] = fmaf(s, wv0.w, acc[3]);
            acc[4] = fmaf(s, wv1.x, acc[4]); acc[5] = fmaf(s, wv1.y, acc[5]);
            acc[6] = fmaf(s, wv1.z, acc[6]); acc[7] = fmaf(s, wv1.w, acc[7]);
        }
    }
    #pragma unroll
    for (int j = 0; j < 8; j++)
        w2[(size_t)row * 32 + e0 + j] = fabsf(acc[j] + bb[e0 + j]);

    if (eq == 0) {
        const float* t3p = t3 + (size_t)row * 32;
        float a = 0.f;
        #pragma unroll
        for (int q = 0; q < 8; q++) {
            float4 v3 = *(const float4*)(t3p + q * 4);
            float4 wv = *(const float4*)&wb[q * 4];
            a = fmaf(v3.x, wv.x, a); a = fmaf(v3.y, wv.y, a);
            a = fmaf(v3.z, wv.z, a); a = fmaf(v3.w, wv.w, a);
        }
        b2v[row] = a + bb2_2[0];
    }
}

// ---------------------------------------------------------------------------
// Kernel B2: fused main GEMM + abs + qs-contraction + elu + w2-dot + out.
// 128 rows/block, 256 threads. Panels of 256 cols (8 n-values).
// Thread: rg=t>>4 (8 rows), cg=t&15 -> n_local=cg>>1, e-half=cg&1 (16 e).
// C-tile 8x16 in regs; hid partial 8x16 in regs; butterfly over n_local.
// W panel LDS layout XOR-swizzled: j' = j ^ (n_local<<2) -> 2-way banks (free).
// ---------------------------------------------------------------------------
__global__ __launch_bounds__(256, 1) void k_main(
        const float* __restrict__ h1g, const float* __restrict__ qsg,
        const float* __restrict__ w12, const float* __restrict__ b12,
        const float* __restrict__ b1vg, const float* __restrict__ w2g,
        const float* __restrict__ b2vg, float* __restrict__ out) {
    __shared__ float sm[36864];       // 144 KB
    float* h1T = sm;                  // [64][128]
    float* Wp  = sm + 8192;           // [64][256] swizzled
    float* qsT = sm + 24576;          // [64][128]
    float* hid = sm + 32768;          // [128][32]

    int t = threadIdx.x;
    int row0 = blockIdx.x * 128;

    // stage h1T and qsT (transpose): thread loads row r=t>>1, 32 h at h0
    {
        int r = t >> 1, h0 = (t & 1) * 32;
        const float* hp = h1g + (size_t)(row0 + r) * 64 + h0;
        const float* qp = qsg + (size_t)(row0 + r) * 64 + h0;
        #pragma unroll
        for (int q = 0; q < 8; q++) {
            float4 hv = *(const float4*)(hp + q * 4);
            float4 qv = *(const float4*)(qp + q * 4);
            int hb = h0 + q * 4;
            h1T[(hb + 0) * 128 + r] = hv.x; h1T[(hb + 1) * 128 + r] = hv.y;
            h1T[(hb + 2) * 128 + r] = hv.z; h1T[(hb + 3) * 128 + r] = hv.w;
            qsT[(hb + 0) * 128 + r] = qv.x; qsT[(hb + 1) * 128 + r] = qv.y;
            qsT[(hb + 2) * 128 + r] = qv.z; qsT[(hb + 3) * 128 + r] = qv.w;
        }
    }

    int rg = t >> 4, cg = t & 15;
    int n_l = cg >> 1, eh = cg & 1;
    int r0 = rg * 8;
    int e0 = eh * 16;
    int jbase = n_l * 32 + e0;
    int xorc = n_l << 2;

    float hacc[8][16];
    #pragma unroll
    for (int i = 0; i < 8; i++)
        #pragma unroll
        for (int jj = 0; jj < 16; jj++) hacc[i][jj] = 0.f;

    for (int p = 0; p < 8; ++p) {
        __syncthreads();   // previous panel's reads done (also fences staging)
        // stage W panel: w1_2[h][p*256 + c], swizzled store
        {
            int c4 = (t & 63) * 4;
            int hh0 = t >> 6;
            int csw = c4 ^ (((c4 >> 5) & 7) << 2);
            const float* wsrc = w12 + (size_t)hh0 * 2048 + p * 256 + c4;
            #pragma unroll
            for (int hh = 0; hh < 16; ++hh) {
                float4 wv = *(const float4*)(wsrc + (size_t)hh * 4 * 2048);
                *(float4*)&Wp[(hh * 4 + hh0) * 256 + csw] = wv;
            }
        }
        __syncthreads();

        int n = p * 8 + n_l;
        float c[8][16];
        {
            float biasv[16];
            #pragma unroll
            for (int q = 0; q < 4; q++)
                *(float4*)&biasv[q * 4] = *(const float4*)(b12 + n * 32 + e0 + q * 4);
            #pragma unroll
            for (int i = 0; i < 8; i++)
                #pragma unroll
                for (int jj = 0; jj < 16; jj++) c[i][jj] = biasv[jj];
        }

        #pragma unroll 2
        for (int k = 0; k < 64; k++) {
            float a[8], w[16];
            *(float4*)&a[0] = *(const float4*)&h1T[k * 128 + r0];
            *(float4*)&a[4] = *(const float4*)&h1T[k * 128 + r0 + 4];
            #pragma unroll
            for (int q = 0; q < 4; q++) {
                int j = (jbase + q * 4) ^ xorc;
                *(float4*)&w[q * 4] = *(const float4*)&Wp[k * 256 + j];
            }
            #pragma unroll
            for (int i = 0; i < 8; i++)
                #pragma unroll
                for (int jj = 0; jj < 16; jj++)
                    c[i][jj] = fmaf(a[i], w[jj], c[i][jj]);
        }

        // fold: hid += qs[n][r] * |C|
        float qv[8];
        *(float4*)&qv[0] = *(const float4*)&qsT[n * 128 + r0];
        *(float4*)&qv[4] = *(const float4*)&qsT[n * 128 + r0 + 4];
        #pragma unroll
        for (int i = 0; i < 8; i++)
            #pragma unroll
            for (int jj = 0; jj < 16; jj++)
                hacc[i][jj] = fmaf(qv[i], fabsf(c[i][jj]), hacc[i][jj]);
    }

    // butterfly-reduce over n_local (lane bits 1..3)
    #pragma unroll
    for (int i = 0; i < 8; i++)
        #pragma unroll
        for (int jj = 0; jj < 16; jj++) {
            float v = hacc[i][jj];
            v += __shfl_xor(v, 2);
            v += __shfl_xor(v, 4);
            v += __shfl_xor(v, 8);
            hacc[i][jj] = v;
        }

    if (n_l == 0) {
        #pragma unroll
        for (int i = 0; i < 8; i++)
            #pragma unroll
            for (int q = 0; q < 4; q++) {
                float4 v = make_float4(hacc[i][q * 4], hacc[i][q * 4 + 1],
                                       hacc[i][q * 4 + 2], hacc[i][q * 4 + 3]);
                *(float4*)&hid[(r0 + i) * 32 + e0 + q * 4] = v;
            }
    }
    __syncthreads();

    // epilogue: per row, hidden = elu(hid + b1v); out = sum(hidden*w2) + b2v
    {
        int r = t >> 1, half = t & 1, he0 = half * 16;
        int row = row0 + r;
        const float* b1p = b1vg + (size_t)row * 32 + he0;
        const float* w2p = w2g + (size_t)row * 32 + he0;
        float accp = 0.f;
        #pragma unroll
        for (int q = 0; q < 4; q++) {
            float4 hv = *(const float4*)&hid[r * 32 + he0 + q * 4];
            float4 bv = *(const float4*)(b1p + q * 4);
            float4 wv = *(const float4*)(w2p + q * 4);
            float x;
            x = hv.x + bv.x; x = x > 0.f ? x : expm1f(x); accp = fmaf(x, wv.x, accp);
            x = hv.y + bv.y; x = x > 0.f ? x : expm1f(x); accp = fmaf(x, wv.y, accp);
            x = hv.z + bv.z; x = x > 0.f ? x : expm1f(x); accp = fmaf(x, wv.z, accp);
            x = hv.w + bv.w; x = x > 0.f ? x : expm1f(x); accp = fmaf(x, wv.w, accp);
        }
        accp += __shfl_xor(accp, 1);
        if (half == 0) out[row] = accp + b2vg[row];
    }
}

// ---------------------------------------------------------------------------
extern "C" void kernel_launch(void* const* d_in, const int* in_sizes, int n_in,
                              void* d_out, int out_size, void* d_ws, size_t ws_size,
                              hipStream_t stream) {
    const float* agent_qs = (const float*)d_in[0];
    const float* obs      = (const float*)d_in[1];
    const int*   agent_mask = (const int*)d_in[2];
    const float* w1_1 = (const float*)d_in[3];
    const float* b1_1 = (const float*)d_in[4];
    const float* w1_2 = (const float*)d_in[5];
    const float* b1_2 = (const float*)d_in[6];
    const float* w2_1 = (const float*)d_in[7];
    const float* b2_1 = (const float*)d_in[8];
    const float* w2_2 = (const float*)d_in[9];
    const float* b2_2 = (const float*)d_in[10];
    const float* wb1  = (const float*)d_in[11];
    const float* bb1  = (const float*)d_in[12];
    const float* wb2_1 = (const float*)d_in[13];
    const float* bb2_1 = (const float*)d_in[14];
    const float* wb2_2 = (const float*)d_in[15];
    const float* bb2_2 = (const float*)d_in[16];

    float* ws = (float*)d_ws;
    float* states = ws;                         // BT*132 = 4,325,376
    float* h1  = states + (size_t)BT * SP;      // BT*64
    float* t2  = h1  + (size_t)BT * 64;         // BT*64
    float* b1v = t2  + (size_t)BT * 64;         // BT*32
    float* t3  = b1v + (size_t)BT * 32;         // BT*32
    float* w2  = t3  + (size_t)BT * 32;         // BT*32
    float* b2v = w2  + (size_t)BT * 32;         // BT
    float* outp = (float*)d_out;

    k_states<<<BT / 4, 256, 0, stream>>>(obs, agent_mask, states);
    k_mlp1<<<BT / 128, 256, 0, stream>>>(states, w1_1, b1_1, w2_1, b2_1,
                                         wb1, bb1, wb2_1, bb2_1, h1, t2, b1v, t3);
    k_w2<<<BT / 64, 256, 0, stream>>>(t2, t3, w2_2, b2_2, wb2_2, bb2_2, w2, b2v);
    k_main<<<BT / 128, 256, 0, stream>>>(h1, agent_qs, w1_2, b1_2, b1v, w2, b2v, outp);
}

// Round 4
// 559.860 us; speedup vs baseline: 1.0922x; 1.0922x over previous
//
#include <hip/hip_runtime.h>
#include <math.h>

// Problem constants
#define BB 128
#define TT 256
#define NN 64
#define OO 32
#define EE 32
#define HH 64
#define SS 129
#define BT 32768      // B*T
#define SP 132        // padded state pitch (multiple of 4)

// ---------------------------------------------------------------------------
// Kernel A: state features. One wave per (b,t) row.
// lane l: o = l&31, half = l>>5; reduce over agents n = half, half+2, ... < k
// ---------------------------------------------------------------------------
__global__ __launch_bounds__(256) void k_states(const float* __restrict__ obs,
                                                const int* __restrict__ mask,
                                                float* __restrict__ states) {
    int w = threadIdx.x >> 6;
    int l = threadIdx.x & 63;
    int bt = blockIdx.x * 4 + w;
    int b = bt >> 8;   // T = 256

    // k = number of active agents for this batch row (count-based mask)
    int kv = mask[(b << 6) + l];
    #pragma unroll
    for (int off = 32; off; off >>= 1) kv += __shfl_xor(kv, off);

    int o = l & 31, nh = l >> 5;
    float sum = 0.f, ssq = 0.f, mn = INFINITY, mx = -INFINITY;
    const float* op = obs + ((size_t)bt << 11);   // bt * N * O
    for (int n = nh; n < kv; n += 2) {
        float v = op[(n << 5) + o];
        sum += v;
        ssq = fmaf(v, v, ssq);
        mn = fminf(mn, v);
        mx = fmaxf(mx, v);
    }
    sum += __shfl_xor(sum, 32);
    ssq += __shfl_xor(ssq, 32);
    mn = fminf(mn, __shfl_xor(mn, 32));
    mx = fmaxf(mx, __shfl_xor(mx, 32));

    float kf = (float)kv;
    float mean = sum / fmaxf(kf, 1.f);
    float var = (ssq - kf * mean * mean) / fmaxf(kf - 1.f, 1.f);
    float sd = (kv > 1) ? sqrtf(fmaxf(var, 0.f)) : 0.f;
    if (kv == 0) { mean = 0.f; sd = 0.f; mn = 0.f; mx = 0.f; }

    float* sp = states + (size_t)bt * SP;
    if (l < 32) {
        sp[o] = mean;
        sp[32 + o] = sd;
        sp[64 + o] = mn;
        sp[96 + o] = mx;
    }
    if (l == 0) {
        sp[128] = kf * 0.015625f;   // ratio = k/64 (0 when k==0, matching ref)
        sp[129] = 0.f; sp[130] = 0.f; sp[131] = 0.f;   // zero pad
    }
}

// ---------------------------------------------------------------------------
// Kernel B1 v2: K=129 GEMM: states(BT x 129) @ Whalf(129 x 96) + bias + act.
// Column halves (blockIdx.y): half0 = [w1_1(64)->h1 relu | wb1(32)->b1v none]
//                             half1 = [w2_1(64)->t2 relu | wb2_1(32)->t3 relu]
// 50 KB LDS -> 3 blocks/CU (3 waves/SIMD).
// 128 rows/block, 256 threads: 32 row-groups x 8 col-groups, 4x12 per thread.
// ---------------------------------------------------------------------------
__global__ __launch_bounds__(256, 3) void k_mlp1(const float* __restrict__ states,
        const float* __restrict__ w1_1, const float* __restrict__ b1_1,
        const float* __restrict__ w2_1, const float* __restrict__ b2_1,
        const float* __restrict__ wb1,  const float* __restrict__ bb1,
        const float* __restrict__ wb2_1,const float* __restrict__ bb2_1,
        float* __restrict__ h1, float* __restrict__ t2,
        float* __restrict__ b1v, float* __restrict__ t3) {
    __shared__ float wl[SP * 96];   // 50,688 B, zero-padded k=129..131
    __shared__ float bl[96];
    int t = threadIdx.x;
    int half = blockIdx.y;

    const float* wA = half ? w2_1 : w1_1;   // 129 x 64
    const float* wB = half ? wb2_1 : wb1;   // 129 x 32
    const float* bA = half ? b2_1 : b1_1;
    const float* bB = half ? bb2_1 : bb1;
    float* outA = half ? t2 : h1;           // pitch 64
    float* outB = half ? t3 : b1v;          // pitch 32
    int reluB = half;                       // b1v cols have no relu

    for (int idx = t; idx < SP * 96; idx += 256) {
        int k = idx / 96;
        int c = idx - k * 96;
        float v = 0.f;
        if (k < SS) v = (c < 64) ? wA[k * 64 + c] : wB[k * 32 + (c - 64)];
        wl[idx] = v;
    }
    if (t < 96) bl[t] = (t < 64) ? bA[t] : bB[t - 64];
    __syncthreads();

    int cg = t & 7, rg = t >> 3;
    int c0 = cg * 12;
    int row0 = blockIdx.x * 128 + rg * 4;
    float acc[4][12];
    #pragma unroll
    for (int i = 0; i < 4; i++)
        #pragma unroll
        for (int j = 0; j < 12; j++) acc[i][j] = 0.f;

    const float* s0 = states + (size_t)row0 * SP;
    for (int k0 = 0; k0 < SP; k0 += 4) {
        float sv[4][4];
        #pragma unroll
        for (int i = 0; i < 4; i++)
            *(float4*)&sv[i][0] = *(const float4*)(s0 + i * SP + k0);
        #pragma unroll
        for (int kk = 0; kk < 4; kk++) {
            float wv[12];
            #pragma unroll
            for (int q = 0; q < 3; q++)
                *(float4*)&wv[q * 4] = *(const float4*)&wl[(k0 + kk) * 96 + c0 + q * 4];
            #pragma unroll
            for (int i = 0; i < 4; i++) {
                float s = sv[i][kk];
                #pragma unroll
                for (int j = 0; j < 12; j++) acc[i][j] = fmaf(s, wv[j], acc[i][j]);
            }
        }
    }

    #pragma unroll
    for (int i = 0; i < 4; i++) {
        int row = row0 + i;
        #pragma unroll
        for (int j = 0; j < 12; j++) {
            int c = c0 + j;
            float v = acc[i][j] + bl[c];
            if (c < 64) {
                v = fmaxf(v, 0.f);
                outA[(size_t)row * 64 + c] = v;
            } else {
                if (reluB) v = fmaxf(v, 0.f);
                outB[(size_t)row * 32 + (c - 64)] = v;
            }
        }
    }
}

// ---------------------------------------------------------------------------
// Kernel B3: w2 = |t2 @ w2_2 + b2_2| (BTx32), b2v = t3 @ wb2_2 + bb2_2 (BT)
// 64 rows/block, 256 threads: 4 threads/row, 8 e-cols each.
// ---------------------------------------------------------------------------
__global__ __launch_bounds__(256) void k_w2(const float* __restrict__ t2,
        const float* __restrict__ t3, const float* __restrict__ w2_2,
        const float* __restrict__ b2_2, const float* __restrict__ wb2_2,
        const float* __restrict__ bb2_2,
        float* __restrict__ w2, float* __restrict__ b2v) {
    __shared__ float wl[64 * 32];
    __shared__ float wb[32];
    __shared__ float bb[32];
    int t = threadIdx.x;
    for (int idx = t; idx < 2048; idx += 256) wl[idx] = w2_2[idx];
    if (t < 32) wb[t] = wb2_2[t];
    if (t >= 32 && t < 64) bb[t - 32] = b2_2[t - 32];
    __syncthreads();

    int r = t >> 2, eq = t & 3;
    int row = blockIdx.x * 64 + r;
    int e0 = eq * 8;
    float acc[8];
    #pragma unroll
    for (int j = 0; j < 8; j++) acc[j] = 0.f;

    const float* tp = t2 + (size_t)row * 64;
    for (int h4 = 0; h4 < 64; h4 += 4) {
        float tv[4];
        *(float4*)tv = *(const float4*)(tp + h4);
        #pragma unroll
        for (int hh = 0; hh < 4; hh++) {
            float s = tv[hh];
            float4 wv0 = *(const float4*)&wl[(h4 + hh) * 32 + e0];
            float4 wv1 = *(const float4*)&wl[(h4 + hh) * 32 + e0 + 4];
            acc[0] = fmaf(s, wv0.x, acc[0]); acc[1] = fmaf(s, wv0.y, acc[1]);
            acc[2] = fmaf(s, wv0.z, acc[2]); acc[3] = fmaf(s, wv0.w, acc[3]);
            acc[4] = fmaf(s, wv1.x, acc[4]); acc[5] = fmaf(s, wv1.y, acc[5]);
            acc[6] = fmaf(s, wv1.z, acc[6]); acc[7] = fmaf(s, wv1.w, acc[7]);
        }
    }
    #pragma unroll
    for (int j = 0; j < 8; j++)
        w2[(size_t)row * 32 + e0 + j] = fabsf(acc[j] + bb[e0 + j]);

    if (eq == 0) {
        const float* t3p = t3 + (size_t)row * 32;
        float a = 0.f;
        #pragma unroll
        for (int q = 0; q < 8; q++) {
            float4 v3 = *(const float4*)(t3p + q * 4);
            float4 wv = *(const float4*)&wb[q * 4];
            a = fmaf(v3.x, wv.x, a); a = fmaf(v3.y, wv.y, a);
            a = fmaf(v3.z, wv.z, a); a = fmaf(v3.w, wv.w, a);
        }
        b2v[row] = a + bb2_2[0];
    }
}

// ---------------------------------------------------------------------------
// Kernel B2 v2: fused main GEMM + abs + qs-contraction + elu + w2-dot + out.
// 64 rows/block (512 blocks), 256 threads. Panels of 64 cols (2 n-values).
// Thread: rg=t>>4 (4 rows), cg=t&15 -> n_l=cg>>3, e0=(cg&7)*4 (4 e).
// C-tile 4x4, hacc 4x4 -> ~80 VGPR. LDS 40 KB -> 4 blocks/CU, 4 waves/SIMD.
// All LDS reads conflict-free (contiguous 16 x 16B or broadcast).
// ---------------------------------------------------------------------------
__global__ __launch_bounds__(256, 4) void k_main(
        const float* __restrict__ h1g, const float* __restrict__ qsg,
        const float* __restrict__ w12, const float* __restrict__ b12,
        const float* __restrict__ b1vg, const float* __restrict__ w2g,
        const float* __restrict__ b2vg, float* __restrict__ out) {
    __shared__ float h1T[64 * 64];    // [h][row] 16 KB
    __shared__ float Wp[64 * 64];     // [h][panel-col] 16 KB
    __shared__ float hid[64 * 32];    // 8 KB
    int t = threadIdx.x;
    int row0 = blockIdx.x * 64;

    // stage h1 transposed: thread r=t>>2, h0=(t&3)*16, 16 scalar LDS writes
    {
        int r = t >> 2, h0 = (t & 3) * 16;
        const float* hp = h1g + (size_t)(row0 + r) * 64 + h0;
        #pragma unroll
        for (int q = 0; q < 4; q++) {
            float4 hv = *(const float4*)(hp + q * 4);
            int hb = h0 + q * 4;
            h1T[(hb + 0) * 64 + r] = hv.x;
            h1T[(hb + 1) * 64 + r] = hv.y;
            h1T[(hb + 2) * 64 + r] = hv.z;
            h1T[(hb + 3) * 64 + r] = hv.w;
        }
    }

    int rg = t >> 4, cg = t & 15;
    int n_l = cg >> 3;
    int e0 = (cg & 7) * 4;
    int r0 = rg * 4;
    int jcol = n_l * 32 + e0;

    float hacc[4][4];
    #pragma unroll
    for (int i = 0; i < 4; i++)
        #pragma unroll
        for (int j = 0; j < 4; j++) hacc[i][j] = 0.f;

    for (int p = 0; p < 32; ++p) {
        __syncthreads();   // Wp free to overwrite (and h1T visible for p=0)
        // stage W panel: w12[h][p*64 + c], h = t>>4 (+q*16), c4 = (t&15)*4
        {
            int h = t >> 4, c4 = (t & 15) * 4;
            const float* wsrc = w12 + (size_t)h * 2048 + p * 64 + c4;
            float4 wv[4];
            #pragma unroll
            for (int q = 0; q < 4; q++)
                wv[q] = *(const float4*)(wsrc + (size_t)q * 16 * 2048);
            #pragma unroll
            for (int q = 0; q < 4; q++)
                *(float4*)&Wp[(h + q * 16) * 64 + c4] = wv[q];
        }
        __syncthreads();

        int n = p * 2 + n_l;
        // qs values for the fold (global, L1-hot; issued before k-loop)
        float qv[4];
        #pragma unroll
        for (int i = 0; i < 4; i++)
            qv[i] = qsg[(size_t)(row0 + r0 + i) * 64 + n];

        float c[4][4];
        {
            float bvv[4];
            *(float4*)bvv = *(const float4*)(b12 + n * 32 + e0);
            #pragma unroll
            for (int i = 0; i < 4; i++)
                #pragma unroll
                for (int j = 0; j < 4; j++) c[i][j] = bvv[j];
        }

        #pragma unroll
        for (int k = 0; k < 64; k++) {
            float a[4], w[4];
            *(float4*)a = *(const float4*)&h1T[k * 64 + r0];
            *(float4*)w = *(const float4*)&Wp[k * 64 + jcol];
            #pragma unroll
            for (int i = 0; i < 4; i++)
                #pragma unroll
                for (int j = 0; j < 4; j++)
                    c[i][j] = fmaf(a[i], w[j], c[i][j]);
        }

        #pragma unroll
        for (int i = 0; i < 4; i++)
            #pragma unroll
            for (int j = 0; j < 4; j++)
                hacc[i][j] = fmaf(qv[i], fabsf(c[i][j]), hacc[i][j]);
    }

    // butterfly-reduce over n_l (lane bit 3)
    #pragma unroll
    for (int i = 0; i < 4; i++)
        #pragma unroll
        for (int j = 0; j < 4; j++)
            hacc[i][j] += __shfl_xor(hacc[i][j], 8);

    if (n_l == 0) {
        #pragma unroll
        for (int i = 0; i < 4; i++) {
            float4 v = make_float4(hacc[i][0], hacc[i][1], hacc[i][2], hacc[i][3]);
            *(float4*)&hid[(r0 + i) * 32 + e0] = v;
        }
    }
    __syncthreads();

    // epilogue: 4 threads/row, 8 e each: hidden = elu(hid + b1v); dot w2
    {
        int r = t >> 2, eq = t & 3, he0 = eq * 8;
        int row = row0 + r;
        const float* b1p = b1vg + (size_t)row * 32 + he0;
        const float* w2p = w2g + (size_t)row * 32 + he0;
        float accp = 0.f;
        #pragma unroll
        for (int q = 0; q < 2; q++) {
            float4 hv = *(const float4*)&hid[r * 32 + he0 + q * 4];
            float4 bv = *(const float4*)(b1p + q * 4);
            float4 wv = *(const float4*)(w2p + q * 4);
            float x;
            x = hv.x + bv.x; x = x > 0.f ? x : expm1f(x); accp = fmaf(x, wv.x, accp);
            x = hv.y + bv.y; x = x > 0.f ? x : expm1f(x); accp = fmaf(x, wv.y, accp);
            x = hv.z + bv.z; x = x > 0.f ? x : expm1f(x); accp = fmaf(x, wv.z, accp);
            x = hv.w + bv.w; x = x > 0.f ? x : expm1f(x); accp = fmaf(x, wv.w, accp);
        }
        accp += __shfl_xor(accp, 1);
        accp += __shfl_xor(accp, 2);
        if (eq == 0) out[row] = accp + b2vg[row];
    }
}

// ---------------------------------------------------------------------------
extern "C" void kernel_launch(void* const* d_in, const int* in_sizes, int n_in,
                              void* d_out, int out_size, void* d_ws, size_t ws_size,
                              hipStream_t stream) {
    const float* agent_qs = (const float*)d_in[0];
    const float* obs      = (const float*)d_in[1];
    const int*   agent_mask = (const int*)d_in[2];
    const float* w1_1 = (const float*)d_in[3];
    const float* b1_1 = (const float*)d_in[4];
    const float* w1_2 = (const float*)d_in[5];
    const float* b1_2 = (const float*)d_in[6];
    const float* w2_1 = (const float*)d_in[7];
    const float* b2_1 = (const float*)d_in[8];
    const float* w2_2 = (const float*)d_in[9];
    const float* b2_2 = (const float*)d_in[10];
    const float* wb1  = (const float*)d_in[11];
    const float* bb1  = (const float*)d_in[12];
    const float* wb2_1 = (const float*)d_in[13];
    const float* bb2_1 = (const float*)d_in[14];
    const float* wb2_2 = (const float*)d_in[15];
    const float* bb2_2 = (const float*)d_in[16];

    float* ws = (float*)d_ws;
    float* states = ws;                         // BT*132
    float* h1  = states + (size_t)BT * SP;      // BT*64
    float* t2  = h1  + (size_t)BT * 64;         // BT*64
    float* b1v = t2  + (size_t)BT * 64;         // BT*32
    float* t3  = b1v + (size_t)BT * 32;         // BT*32
    float* w2  = t3  + (size_t)BT * 32;         // BT*32
    float* b2v = w2  + (size_t)BT * 32;         // BT
    float* outp = (float*)d_out;

    k_states<<<BT / 4, 256, 0, stream>>>(obs, agent_mask, states);
    dim3 g1(BT / 128, 2);
    k_mlp1<<<g1, 256, 0, stream>>>(states, w1_1, b1_1, w2_1, b2_1,
                                   wb1, bb1, wb2_1, bb2_1, h1, t2, b1v, t3);
    k_w2<<<BT / 64, 256, 0, stream>>>(t2, t3, w2_2, b2_2, wb2_2, bb2_2, w2, b2v);
    k_main<<<BT / 64, 256, 0, stream>>>(h1, agent_qs, w1_2, b1_2, b1v, w2, b2v, outp);
}